// Round 5
// baseline (1253.780 us; speedup 1.0000x reference)
//
#include <hip/hip_runtime.h>
#include <hip/hip_bf16.h>

#define TTOK 4096   // B*S tokens
#define DIM  2048   // hidden dim
#define FF   4096   // expert ffn dim
#define NE   8      // experts
#define TROWS 8192  // TTOK * top_k routed rows

#define BM 256
#define BK 64       // K-tile
// 8 waves: 2 in M x 4 in N; per-wave output 128x64

typedef __attribute__((ext_vector_type(4))) float  f32x4;
typedef __attribute__((ext_vector_type(8))) short  s16x8;
typedef __attribute__((ext_vector_type(8))) unsigned short u16x8;

__device__ __forceinline__ unsigned short f2bf(float f) {
  union { __hip_bfloat16 h; unsigned short u; } cv;
  cv.h = __float2bfloat16(f);
  return cv.u;
}
__device__ __forceinline__ float bf2f(unsigned short u) {
  union { unsigned int i; float f; } cv;
  cv.i = ((unsigned int)u) << 16;
  return cv.f;
}

// async global->LDS, 16B per lane; dest = wave-uniform base, HW adds lane*16.
__device__ __forceinline__ void gl_lds16(const void* g, void* s) {
  __builtin_amdgcn_global_load_lds(
      (__attribute__((address_space(1))) void*)(g),
      (__attribute__((address_space(3))) void*)(s), 16, 0, 0);
}

#define VMW(NN) asm volatile("s_waitcnt vmcnt(" #NN ")" ::: "memory")

// ---------------- f32 -> bf16 bulk convert (8 elems/thread) -----------------
__global__ __launch_bounds__(256) void cvt_kernel(const float* __restrict__ s,
                                                  unsigned short* __restrict__ d, int n8) {
  int i = blockIdx.x * 256 + threadIdx.x;
  if (i >= n8) return;
  f32x4 v0 = *(const f32x4*)(s + (size_t)i * 8);
  f32x4 v1 = *(const f32x4*)(s + (size_t)i * 8 + 4);
  u16x8 o;
#pragma unroll
  for (int j = 0; j < 4; ++j) { o[j] = f2bf(v0[j]); o[j + 4] = f2bf(v1[j]); }
  *(u16x8*)(d + (size_t)i * 8) = o;
}

// ---------------- router ----------------------------------------------------
__global__ void router_kernel(const float* __restrict__ x,
                              const float* __restrict__ gate_w,
                              int* __restrict__ tope, float* __restrict__ topw,
                              int* __restrict__ counts) {
  const int t = blockIdx.x;
  const int tid = threadIdx.x;
  const float* xr = x + (size_t)t * DIM;
  float p[NE];
#pragma unroll
  for (int e = 0; e < NE; ++e) p[e] = 0.f;
  for (int d = tid; d < DIM; d += 256) {
    float xv = xr[d];
#pragma unroll
    for (int e = 0; e < NE; ++e) p[e] += xv * gate_w[e * DIM + d];
  }
#pragma unroll
  for (int off = 32; off > 0; off >>= 1) {
#pragma unroll
    for (int e = 0; e < NE; ++e) p[e] += __shfl_down(p[e], off);
  }
  __shared__ float red[4][NE];
  const int wid = tid >> 6, lane = tid & 63;
  if (lane == 0) {
#pragma unroll
    for (int e = 0; e < NE; ++e) red[wid][e] = p[e];
  }
  __syncthreads();
  if (tid == 0) {
    float l[NE];
#pragma unroll
    for (int e = 0; e < NE; ++e) l[e] = red[0][e] + red[1][e] + red[2][e] + red[3][e];
    float mx = l[0];
#pragma unroll
    for (int e = 1; e < NE; ++e) mx = fmaxf(mx, l[e]);
    float pr[NE]; float sum = 0.f;
#pragma unroll
    for (int e = 0; e < NE; ++e) { pr[e] = __expf(l[e] - mx); sum += pr[e]; }
    float inv = 1.f / sum;
#pragma unroll
    for (int e = 0; e < NE; ++e) pr[e] *= inv;
    int i0 = 0; float p0 = pr[0];
#pragma unroll
    for (int e = 1; e < NE; ++e) if (pr[e] > p0) { p0 = pr[e]; i0 = e; }
    int i1 = -1; float p1 = -1.f;
#pragma unroll
    for (int e = 0; e < NE; ++e) if (e != i0 && pr[e] > p1) { p1 = pr[e]; i1 = e; }
    float wsum = p0 + p1;
    tope[t * 2 + 0] = i0; topw[t * 2 + 0] = p0 / wsum;
    tope[t * 2 + 1] = i1; topw[t * 2 + 1] = p1 / wsum;
    atomicAdd(&counts[i0], 1);
    atomicAdd(&counts[i1], 1);
  }
}

__global__ void prefix_kernel(const int* __restrict__ counts, int* __restrict__ basep) {
  if (threadIdx.x == 0 && blockIdx.x == 0) {
    int acc = 0;
    for (int e = 0; e < NE; ++e) { basep[e] = acc; acc += counts[e]; }
  }
}

__global__ void fill_kernel(const int* __restrict__ tope, const float* __restrict__ topw,
                            const int* __restrict__ basep, int* __restrict__ fillp,
                            int* __restrict__ rowtok, float* __restrict__ roww,
                            int* __restrict__ rowof) {
  int t = blockIdx.x * blockDim.x + threadIdx.x;
  if (t >= TTOK) return;
#pragma unroll
  for (int s = 0; s < 2; ++s) {
    int e = tope[t * 2 + s];
    int r = basep[e] + atomicAdd(&fillp[e], 1);
    rowtok[r] = t;
    roww[r] = topw[t * 2 + s];
    rowof[t * 2 + s] = r;
  }
}

// ====== 256x256 / BK=64 / 8-wave, 4-phase-per-tile counted-vmcnt GEMM =======
// Phases per K-tile: (kk0,mlo)(kk0,mhi)(kk1,mlo)(kk1,mhi); 16 MFMA each.
// Stage spreading (per wave): p0: A{0,2}(t+1); p1: A{1,3}(t+1); p3: B{0..3}(t+2).
// Issue order == consumption order -> vmcnt(8) exact at p0/p1; no drain in loop.
// MODE 0: A rows gathered via rowtok (xb), C -> bf16 store.
// MODE 1: A rows contiguous (H), C * roww[row] -> f32 store.
template <int MODE, int K, int N>
__global__ __launch_bounds__(512, 1) void gemm8(
    const unsigned short* __restrict__ Asrc, const unsigned short* __restrict__ Bw,
    const int* __restrict__ rowtok, const float* __restrict__ roww,
    const int* __restrict__ counts, const int* __restrict__ basep,
    void* __restrict__ Out) {
  const int e = blockIdx.z;
  const int cnt = counts[e];
  const int m0 = blockIdx.y * BM;
  if (m0 >= cnt) return;
  const int n0 = blockIdx.x * BM;   // BN == BM == 256
  const int base_e = basep[e];

  __shared__ unsigned short As[2][BM * BK];   // 2 x 32 KiB
  __shared__ unsigned short Bs[2][BM * BK];   // 2 x 32 KiB

  const int tid = threadIdx.x;
  const int lane = tid & 63;
  const int w = tid >> 6;          // 0..7
  const int wm = w >> 2;           // 0..1  (M half)
  const int wn = w & 3;            // 0..3  (N quarter)

  // ---- staging geometry: group s covers rows s*64..+63; wave w rows w*8..+7 ----
  const int lsub  = lane >> 3;     // row within 8-row group
  const int lslot = lane & 7;      // 16B slot within 128B row
  // pre-swizzled global source: physical slot lslot holds logical (lslot^lsub)
  const int swz_e = 8 * (lslot ^ lsub);

  const unsigned short* pA[4];
  const unsigned short* pB[4];
#pragma unroll
  for (int s = 0; s < 4; ++s) {
    int rl = s * 64 + w * 8 + lsub;           // row in tile 0..255
    int ga = m0 + rl; if (ga > cnt - 1) ga = cnt - 1;
    if (MODE == 0) {
      int tok = rowtok[base_e + ga];
      pA[s] = Asrc + (size_t)tok * K + swz_e;
    } else {
      pA[s] = Asrc + (size_t)(base_e + ga) * K + swz_e;
    }
    pB[s] = Bw + ((size_t)e * N + n0 + s * 64 + w * 8 + lsub) * K + swz_e;
  }

  // ---- fragment geometry ----
  const int frow = lane & 15;
  const int klane = lane >> 4;     // 0..3
  const int ks0 = (klane * 8) ^ ((frow & 7) * 8);        // kk0 swizzled col
  const int ks1 = (32 + klane * 8) ^ ((frow & 7) * 8);   // kk1 swizzled col

  f32x4 acc[8][4];
#pragma unroll
  for (int mf = 0; mf < 8; ++mf)
#pragma unroll
    for (int nf = 0; nf < 4; ++nf) acc[mf][nf] = (f32x4)0.f;

  // WORK: 4 a-frag reads (+optional 4 b-frag reads into bfr) + 16 MFMA.
#define WORK(ACP, BCP, MH, KS, LOADB) do { \
    s16x8 afr[4]; \
    _Pragma("unroll") \
    for (int ii = 0; ii < 4; ++ii) \
      afr[ii] = *(const s16x8*)&(ACP)[(size_t)(wm * 128 + (MH) * 64 + ii * 16 + frow) * BK + (KS)]; \
    if (LOADB) { \
      _Pragma("unroll") \
      for (int nf = 0; nf < 4; ++nf) \
        bfr[nf] = *(const s16x8*)&(BCP)[(size_t)(wn * 64 + nf * 16 + frow) * BK + (KS)]; \
    } \
    __builtin_amdgcn_s_setprio(1); \
    _Pragma("unroll") \
    for (int ii = 0; ii < 4; ++ii) \
      _Pragma("unroll") \
      for (int nf = 0; nf < 4; ++nf) \
        acc[(MH) * 4 + ii][nf] = \
            __builtin_amdgcn_mfma_f32_16x16x32_bf16(afr[ii], bfr[nf], acc[(MH) * 4 + ii][nf], 0, 0, 0); \
    __builtin_amdgcn_s_setprio(0); \
  } while (0)

  const int NT = K / BK;

  // ---- prologue: B(t0)x4, A0,A2(t0), A1,A3(t0), B(t1)x4  (order = ledger) ----
#pragma unroll
  for (int s = 0; s < 4; ++s)
    gl_lds16(pB[s], &Bs[0][(s * 64 + w * 8) * BK]);
  gl_lds16(pA[0], &As[0][(0   + w * 8) * BK]);
  gl_lds16(pA[2], &As[0][(128 + w * 8) * BK]);
  gl_lds16(pA[1], &As[0][(64  + w * 8) * BK]);
  gl_lds16(pA[3], &As[0][(192 + w * 8) * BK]);
#pragma unroll
  for (int s = 0; s < 4; ++s)
    gl_lds16(pB[s] + BK, &Bs[1][(s * 64 + w * 8) * BK]);

  for (int t = 0; t < NT - 1; ++t) {
    const int cb = t & 1;
    const unsigned short* Ac = &As[cb][0];
    const unsigned short* Bc = &Bs[cb][0];
    unsigned short* An = &As[cb ^ 1][0];          // A(t+1) target
    unsigned short* Bn = &Bs[cb][0];              // B(t+2) target (parity t)
    const size_t koffA = (size_t)(t + 1) * BK;
    const size_t koffB = (size_t)(t + 2) * BK;
    s16x8 bfr[4];

    // ---- phase 0: (kk0, mlo) ----
    gl_lds16(pA[0] + koffA, &An[(0   + w * 8) * BK]);
    gl_lds16(pA[2] + koffA, &An[(128 + w * 8) * BK]);
    VMW(8);
    __builtin_amdgcn_s_barrier();
    WORK(Ac, Bc, 0, ks0, 1);
    __builtin_amdgcn_s_barrier();

    // ---- phase 1: (kk0, mhi) ----
    gl_lds16(pA[1] + koffA, &An[(64  + w * 8) * BK]);
    gl_lds16(pA[3] + koffA, &An[(192 + w * 8) * BK]);
    VMW(8);
    __builtin_amdgcn_s_barrier();
    WORK(Ac, Bc, 1, ks0, 0);
    __builtin_amdgcn_s_barrier();

    // ---- phase 2: (kk1, mlo) ----
    WORK(Ac, Bc, 0, ks1, 1);
    __builtin_amdgcn_s_barrier();

    // ---- phase 3: (kk1, mhi); B region of cur buf dead after p2 ----
    if (t < NT - 2) {
#pragma unroll
      for (int s = 0; s < 4; ++s)
        gl_lds16(pB[s] + koffB, &Bn[(s * 64 + w * 8) * BK]);
    }
    WORK(Ac, Bc, 1, ks1, 0);
    __builtin_amdgcn_s_barrier();
  }

  // ---- peeled last tile (no issues; exact tail vmcnt) ----
  {
    const int cb = (NT - 1) & 1;
    const unsigned short* Ac = &As[cb][0];
    const unsigned short* Bc = &Bs[cb][0];
    s16x8 bfr[4];
    VMW(2);
    __builtin_amdgcn_s_barrier();
    WORK(Ac, Bc, 0, ks0, 1);
    __builtin_amdgcn_s_barrier();
    VMW(0);
    __builtin_amdgcn_s_barrier();
    WORK(Ac, Bc, 1, ks0, 0);
    __builtin_amdgcn_s_barrier();
    WORK(Ac, Bc, 0, ks1, 1);
    __builtin_amdgcn_s_barrier();
    WORK(Ac, Bc, 1, ks1, 0);
  }
#undef WORK

  // ---- epilogue: acc[mf] row = wm*128 + (mf>>2)*64 + (mf&3)*16 ----
#pragma unroll
  for (int mf = 0; mf < 8; ++mf) {
#pragma unroll
    for (int nf = 0; nf < 4; ++nf) {
      int col = n0 + wn * 64 + nf * 16 + frow;
#pragma unroll
      for (int j = 0; j < 4; ++j) {
        int rl = wm * 128 + (mf >> 2) * 64 + (mf & 3) * 16 + klane * 4 + j;
        int grow = m0 + rl;
        if (grow < cnt) {
          if (MODE == 0) {
            ((unsigned short*)Out)[(size_t)(base_e + grow) * N + col] = f2bf(acc[mf][nf][j]);
          } else {
            float wv = roww[base_e + grow];
            ((float*)Out)[(size_t)(base_e + grow) * N + col] = acc[mf][nf][j] * wv;
          }
        }
      }
    }
  }
}

// H = silu(h1) * h3, elementwise, in-place capable (out == h1)
__global__ __launch_bounds__(256) void swiglu_kernel(const unsigned short* __restrict__ h1,
                                                     const unsigned short* __restrict__ h3,
                                                     unsigned short* __restrict__ H, int n8) {
  int i = blockIdx.x * 256 + threadIdx.x;
  if (i >= n8) return;
  u16x8 v1 = *(const u16x8*)(h1 + (size_t)i * 8);
  u16x8 v3 = *(const u16x8*)(h3 + (size_t)i * 8);
  u16x8 o;
#pragma unroll
  for (int j = 0; j < 8; ++j) {
    float s = bf2f(v1[j]);
    float g = bf2f(v3[j]);
    o[j] = f2bf((s / (1.f + __expf(-s))) * g);
  }
  *(u16x8*)(H + (size_t)i * 8) = o;
}

// y[t,:] = R[row0(t),:] + R[row1(t),:]
__global__ __launch_bounds__(256) void combine_kernel(const float* __restrict__ R,
                                                      const int* __restrict__ rowof,
                                                      float* __restrict__ y) {
  int idx = blockIdx.x * 256 + threadIdx.x;
  int t = idx >> 9;                           // D/4 = 512
  int d4 = idx & 511;
  int r0 = rowof[t * 2], r1 = rowof[t * 2 + 1];
  f32x4 a = *(const f32x4*)(R + (size_t)r0 * DIM + d4 * 4);
  f32x4 b = *(const f32x4*)(R + (size_t)r1 * DIM + d4 * 4);
  *(f32x4*)(y + (size_t)t * DIM + d4 * 4) = a + b;
}

extern "C" void kernel_launch(void* const* d_in, const int* in_sizes, int n_in,
                              void* d_out, int out_size, void* d_ws, size_t ws_size,
                              hipStream_t stream) {
  const float* x      = (const float*)d_in[0];
  const float* gate_w = (const float*)d_in[1];
  const float* w1     = (const float*)d_in[2];
  const float* w2     = (const float*)d_in[3];
  const float* w3     = (const float*)d_in[4];
  float* y = (float*)d_out;

  char* ws = (char*)d_ws;
  const size_t MB = 1ull << 20;
  // control block
  int*   tope   = (int*)(ws);
  float* topw   = (float*)(ws + (32 << 10));
  int*   rowtok = (int*)(ws + (64 << 10));
  float* roww   = (float*)(ws + (96 << 10));
  int*   rowof  = (int*)(ws + (128 << 10));
  int*   counts = (int*)(ws + (160 << 10));
  int*   basep  = counts + 32;
  int*   fillp  = counts + 64;

  unsigned short* xb  = (unsigned short*)(ws + 1 * MB);    // 16 MB
  unsigned short* H1  = (unsigned short*)(ws + 17 * MB);   // 64 MB (h1, then H in-place)
  unsigned short* H3  = (unsigned short*)(ws + 81 * MB);   // 64 MB
  unsigned short* w1b = (unsigned short*)(ws + 145 * MB);  // 128 MB
  unsigned short* w3b = (unsigned short*)(ws + 273 * MB);  // 128 MB
  unsigned short* w2b = (unsigned short*)(ws + 401 * MB);  // 128 MB (end 529)
  float*          R   = (float*)(ws + 145 * MB);           // 64 MB, aliases dead w1b

  hipMemsetAsync(counts, 0, 512, stream);
  router_kernel<<<TTOK, 256, 0, stream>>>(x, gate_w, tope, topw, counts);
  prefix_kernel<<<1, 64, 0, stream>>>(counts, basep);
  fill_kernel<<<TTOK / 256, 256, 0, stream>>>(tope, topw, basep, fillp, rowtok, roww, rowof);

  const int nw8 = NE * FF * DIM / 8;
  const int nx8 = TTOK * DIM / 8;
  cvt_kernel<<<nw8 / 256, 256, 0, stream>>>(w1, w1b, nw8);
  cvt_kernel<<<nw8 / 256, 256, 0, stream>>>(w3, w3b, nw8);
  cvt_kernel<<<nw8 / 256, 256, 0, stream>>>(w2, w2b, nw8);
  cvt_kernel<<<nx8 / 256, 256, 0, stream>>>(x, xb, nx8);

  // h1 = Xe @ w1^T ; h3 = Xe @ w3^T   (M=routed rows, N=FF, K=DIM)
  gemm8<0, DIM, FF><<<dim3(FF / BM, 16, NE), 512, 0, stream>>>(
      xb, w1b, rowtok, roww, counts, basep, (void*)H1);
  gemm8<0, DIM, FF><<<dim3(FF / BM, 16, NE), 512, 0, stream>>>(
      xb, w3b, rowtok, roww, counts, basep, (void*)H3);
  swiglu_kernel<<<TROWS * FF / 8 / 256, 256, 0, stream>>>(H1, H3, H1, TROWS * FF / 8);
  // R = roww * (H @ w2^T)   (M=routed rows, N=DIM, K=FF); w1b dead -> R aliases it
  gemm8<1, FF, DIM><<<dim3(DIM / BM, 16, NE), 512, 0, stream>>>(
      H1, w2b, rowtok, roww, counts, basep, (void*)R);
  combine_kernel<<<TTOK * DIM / 4 / 256, 256, 0, stream>>>(R, rowof, y);
}

// Round 6
// 986.417 us; speedup vs baseline: 1.2710x; 1.2710x over previous
//
#include <hip/hip_runtime.h>
#include <hip/hip_bf16.h>

#define TTOK 4096   // B*S tokens
#define DIM  2048   // hidden dim
#define FF   4096   // expert ffn dim
#define NE   8      // experts
#define TROWS 8192  // TTOK * top_k routed rows

#define BM 256
#define BK 64       // K-tile
// 8 waves: 2 in M x 4 in N; per-wave output 128x64

typedef __attribute__((ext_vector_type(4))) float  f32x4;
typedef __attribute__((ext_vector_type(8))) short  s16x8;
typedef __attribute__((ext_vector_type(8))) unsigned short u16x8;

__device__ __forceinline__ unsigned short f2bf(float f) {
  union { __hip_bfloat16 h; unsigned short u; } cv;
  cv.h = __float2bfloat16(f);
  return cv.u;
}
__device__ __forceinline__ float bf2f(unsigned short u) {
  union { unsigned int i; float f; } cv;
  cv.i = ((unsigned int)u) << 16;
  return cv.f;
}

// async global->LDS, 16B per lane; dest = wave-uniform base, HW adds lane*16.
__device__ __forceinline__ void gl_lds16(const void* g, void* s) {
  __builtin_amdgcn_global_load_lds(
      (__attribute__((address_space(1))) void*)(g),
      (__attribute__((address_space(3))) void*)(s), 16, 0, 0);
}

#define VMW(NN) asm volatile("s_waitcnt vmcnt(" #NN ")" ::: "memory")

// ---------------- f32 -> bf16 bulk convert (8 elems/thread) -----------------
__global__ __launch_bounds__(256) void cvt_kernel(const float* __restrict__ s,
                                                  unsigned short* __restrict__ d, int n8) {
  int i = blockIdx.x * 256 + threadIdx.x;
  if (i >= n8) return;
  f32x4 v0 = *(const f32x4*)(s + (size_t)i * 8);
  f32x4 v1 = *(const f32x4*)(s + (size_t)i * 8 + 4);
  u16x8 o;
#pragma unroll
  for (int j = 0; j < 4; ++j) { o[j] = f2bf(v0[j]); o[j + 4] = f2bf(v1[j]); }
  *(u16x8*)(d + (size_t)i * 8) = o;
}

// ---------------- router ----------------------------------------------------
__global__ void router_kernel(const float* __restrict__ x,
                              const float* __restrict__ gate_w,
                              int* __restrict__ tope, float* __restrict__ topw,
                              int* __restrict__ counts) {
  const int t = blockIdx.x;
  const int tid = threadIdx.x;
  const float* xr = x + (size_t)t * DIM;
  float p[NE];
#pragma unroll
  for (int e = 0; e < NE; ++e) p[e] = 0.f;
  for (int d = tid; d < DIM; d += 256) {
    float xv = xr[d];
#pragma unroll
    for (int e = 0; e < NE; ++e) p[e] += xv * gate_w[e * DIM + d];
  }
#pragma unroll
  for (int off = 32; off > 0; off >>= 1) {
#pragma unroll
    for (int e = 0; e < NE; ++e) p[e] += __shfl_down(p[e], off);
  }
  __shared__ float red[4][NE];
  const int wid = tid >> 6, lane = tid & 63;
  if (lane == 0) {
#pragma unroll
    for (int e = 0; e < NE; ++e) red[wid][e] = p[e];
  }
  __syncthreads();
  if (tid == 0) {
    float l[NE];
#pragma unroll
    for (int e = 0; e < NE; ++e) l[e] = red[0][e] + red[1][e] + red[2][e] + red[3][e];
    float mx = l[0];
#pragma unroll
    for (int e = 1; e < NE; ++e) mx = fmaxf(mx, l[e]);
    float pr[NE]; float sum = 0.f;
#pragma unroll
    for (int e = 0; e < NE; ++e) { pr[e] = __expf(l[e] - mx); sum += pr[e]; }
    float inv = 1.f / sum;
#pragma unroll
    for (int e = 0; e < NE; ++e) pr[e] *= inv;
    int i0 = 0; float p0 = pr[0];
#pragma unroll
    for (int e = 1; e < NE; ++e) if (pr[e] > p0) { p0 = pr[e]; i0 = e; }
    int i1 = -1; float p1 = -1.f;
#pragma unroll
    for (int e = 0; e < NE; ++e) if (e != i0 && pr[e] > p1) { p1 = pr[e]; i1 = e; }
    float wsum = p0 + p1;
    tope[t * 2 + 0] = i0; topw[t * 2 + 0] = p0 / wsum;
    tope[t * 2 + 1] = i1; topw[t * 2 + 1] = p1 / wsum;
    atomicAdd(&counts[i0], 1);
    atomicAdd(&counts[i1], 1);
  }
}

__global__ void prefix_kernel(const int* __restrict__ counts, int* __restrict__ basep) {
  if (threadIdx.x == 0 && blockIdx.x == 0) {
    int acc = 0;
    for (int e = 0; e < NE; ++e) { basep[e] = acc; acc += counts[e]; }
  }
}

__global__ void fill_kernel(const int* __restrict__ tope, const float* __restrict__ topw,
                            const int* __restrict__ basep, int* __restrict__ fillp,
                            int* __restrict__ rowtok, float* __restrict__ roww,
                            int* __restrict__ rowof) {
  int t = blockIdx.x * blockDim.x + threadIdx.x;
  if (t >= TTOK) return;
#pragma unroll
  for (int s = 0; s < 2; ++s) {
    int e = tope[t * 2 + s];
    int r = basep[e] + atomicAdd(&fillp[e], 1);
    rowtok[r] = t;
    roww[r] = topw[t * 2 + s];
    rowof[t * 2 + s] = r;
  }
}

// ====== 256x256 / BK=64 / 8-wave, m201-style 8-phase counted-vmcnt GEMM =====
// Per 2 K-tiles (t even in buf0, t+1 in buf1), 8 phases; each phase:
//   {ds_reads ; stage 1 half-tile} -> barrier -> lgkmcnt(0) -> 16 MFMA -> barrier
// Quadrants per tile: (mlo,nlo)(mlo,nhi)(mhi,nhi)(mhi,nlo); b-frags held so
// reads/phase = 12/4/8/0.  Stage ledger: p1,p2:A(t+1); p3,p4:B(t+2);
// p5,p6:A(t+2); p7,p8:B(t+3).  vmcnt(4) ONLY at p4 and p8 (exact gate).
// MODE 0: A rows gathered via rowtok, C -> bf16 store.
// MODE 1: A rows contiguous, C * roww[row] -> f32 store.
template <int MODE, int K, int N>
__global__ __launch_bounds__(512, 1) void gemm8(
    const unsigned short* __restrict__ Asrc, const unsigned short* __restrict__ Bw,
    const int* __restrict__ rowtok, const float* __restrict__ roww,
    const int* __restrict__ counts, const int* __restrict__ basep,
    void* __restrict__ Out) {
  const int e = blockIdx.z;
  const int cnt = counts[e];
  const int m0 = blockIdx.y * BM;
  if (m0 >= cnt) return;
  const int n0 = blockIdx.x * BM;   // BN == BM == 256
  const int base_e = basep[e];

  __shared__ unsigned short As[2][BM * BK];   // 2 x 32 KiB
  __shared__ unsigned short Bs[2][BM * BK];   // 2 x 32 KiB

  const int tid = threadIdx.x;
  const int lane = tid & 63;
  const int w = tid >> 6;          // 0..7
  const int wm = w >> 2;           // 0..1  (M half)
  const int wn = w & 3;            // 0..3  (N quarter)

  // ---- staging geometry: group s covers rows s*64..+63; wave w rows w*8..+7
  const int lsub  = lane >> 3;     // row within 8-row group
  const int lslot = lane & 7;      // 16B slot within 128B row
  // pre-swizzled global source: physical slot lslot holds logical (lslot^lsub)
  const int swz_e = 8 * (lslot ^ lsub);

  const unsigned short* pA[4];
  const unsigned short* pB[4];
#pragma unroll
  for (int s = 0; s < 4; ++s) {
    int rl = s * 64 + w * 8 + lsub;           // row in tile 0..255
    int ga = m0 + rl; if (ga > cnt - 1) ga = cnt - 1;
    if (MODE == 0) {
      int tok = rowtok[base_e + ga];
      pA[s] = Asrc + (size_t)tok * K + swz_e;
    } else {
      pA[s] = Asrc + (size_t)(base_e + ga) * K + swz_e;
    }
    pB[s] = Bw + ((size_t)e * N + n0 + s * 64 + w * 8 + lsub) * K + swz_e;
  }

  // ---- fragment geometry ----
  const int frow = lane & 15;
  const int klane = lane >> 4;     // 0..3
  const int ks0 = (klane * 8) ^ ((frow & 7) * 8);        // kk0 swizzled col
  const int ks1 = (32 + klane * 8) ^ ((frow & 7) * 8);   // kk1 swizzled col

  f32x4 acc[8][4];
#pragma unroll
  for (int mf = 0; mf < 8; ++mf)
#pragma unroll
    for (int nf = 0; nf < 4; ++nf) acc[mf][nf] = (f32x4)0.f;

  // stage macros: one half-tile = 2 gl_lds (= 2 vmcnt units per wave)
#define ST_A(BUF, G0, T) do { \
    gl_lds16(pA[G0]     + (size_t)(T) * BK, &As[BUF][((G0) * 64 + w * 8) * BK]); \
    gl_lds16(pA[(G0)+1] + (size_t)(T) * BK, &As[BUF][(((G0)+1) * 64 + w * 8) * BK]); \
  } while (0)
#define ST_B(BUF, G0, T) do { \
    gl_lds16(pB[G0]     + (size_t)(T) * BK, &Bs[BUF][((G0) * 64 + w * 8) * BK]); \
    gl_lds16(pB[(G0)+1] + (size_t)(T) * BK, &Bs[BUF][(((G0)+1) * 64 + w * 8) * BK]); \
  } while (0)

#define RD_A(MH, BUF) do { \
    _Pragma("unroll") \
    for (int ii = 0; ii < 4; ++ii) { \
      a[ii][0] = *(const s16x8*)&As[BUF][(wm * 128 + (MH) * 64 + ii * 16 + frow) * BK + ks0]; \
      a[ii][1] = *(const s16x8*)&As[BUF][(wm * 128 + (MH) * 64 + ii * 16 + frow) * BK + ks1]; \
    } } while (0)
#define RD_B(DST, NH, BUF) do { \
    _Pragma("unroll") \
    for (int j = 0; j < 2; ++j) { \
      DST[j][0] = *(const s16x8*)&Bs[BUF][(wn * 64 + (NH) * 32 + j * 16 + frow) * BK + ks0]; \
      DST[j][1] = *(const s16x8*)&Bs[BUF][(wn * 64 + (NH) * 32 + j * 16 + frow) * BK + ks1]; \
    } } while (0)

#define MM(MH, NH, BB) do { \
    __builtin_amdgcn_s_setprio(1); \
    _Pragma("unroll") \
    for (int ii = 0; ii < 4; ++ii) \
      _Pragma("unroll") \
      for (int j = 0; j < 2; ++j) { \
        acc[(MH) * 4 + ii][(NH) * 2 + j] = __builtin_amdgcn_mfma_f32_16x16x32_bf16( \
            a[ii][0], BB[j][0], acc[(MH) * 4 + ii][(NH) * 2 + j], 0, 0, 0); \
        acc[(MH) * 4 + ii][(NH) * 2 + j] = __builtin_amdgcn_mfma_f32_16x16x32_bf16( \
            a[ii][1], BB[j][1], acc[(MH) * 4 + ii][(NH) * 2 + j], 0, 0, 0); \
      } \
    __builtin_amdgcn_s_setprio(0); \
  } while (0)

  // mid-phase sync: pin reads/stages before barrier, MFMA after lgkmcnt(0)
#define MIDSYNC do { \
    __builtin_amdgcn_sched_barrier(0); \
    __builtin_amdgcn_s_barrier(); \
    asm volatile("s_waitcnt lgkmcnt(0)" ::: "memory"); \
    __builtin_amdgcn_sched_barrier(0); \
  } while (0)
#define ENDB do { \
    __builtin_amdgcn_sched_barrier(0); \
    __builtin_amdgcn_s_barrier(); \
  } while (0)

  const int NT = K / BK;

  // ---- prologue: age order A0lo,A0hi,B0lo,B0hi,B1lo,B1hi; keep B1 in flight
  ST_A(0, 0, 0); ST_A(0, 2, 0);
  ST_B(0, 0, 0); ST_B(0, 2, 0);
  ST_B(1, 0, 1); ST_B(1, 2, 1);
  VMW(4);
  __builtin_amdgcn_s_barrier();

  s16x8 a[4][2], bl[2][2], bh[2][2];

  for (int t = 0; t < NT; t += 2) {
    const bool full = (t + 2 < NT);   // uniform per block

    // ================= tile t (buf0) =================
    // p1: q(mlo,nlo); stage A-lo(t+1)->buf1
    RD_A(0, 0); RD_B(bl, 0, 0);
    ST_A(1, 0, t + 1);
    MIDSYNC; MM(0, 0, bl); ENDB;

    // p2: q(mlo,nhi); stage A-hi(t+1)->buf1
    RD_B(bh, 1, 0);
    ST_A(1, 2, t + 1);
    MIDSYNC; MM(0, 1, bh); ENDB;

    // p3: q(mhi,nhi); stage B-lo(t+2)->buf0
    RD_A(1, 0);
    if (full) ST_B(0, 0, t + 2);
    MIDSYNC; MM(1, 1, bh); ENDB;

    // p4: q(mhi,nlo) [no reads]; stage B-hi(t+2)->buf0; gate for p5
    if (full) ST_B(0, 2, t + 2);
    MIDSYNC; MM(1, 0, bl);
    if (full) { VMW(4); } else { VMW(0); }
    ENDB;

    // ================= tile t+1 (buf1) =================
    // p5: stage A-lo(t+2)->buf0
    RD_A(0, 1); RD_B(bl, 0, 1);
    if (full) ST_A(0, 0, t + 2);
    MIDSYNC; MM(0, 0, bl); ENDB;

    // p6: stage A-hi(t+2)->buf0
    RD_B(bh, 1, 1);
    if (full) ST_A(0, 2, t + 2);
    MIDSYNC; MM(0, 1, bh); ENDB;

    // p7: stage B-lo(t+3)->buf1
    RD_A(1, 1);
    if (full) ST_B(1, 0, t + 3);
    MIDSYNC; MM(1, 1, bh); ENDB;

    // p8: stage B-hi(t+3)->buf1; gate for next p1
    if (full) ST_B(1, 2, t + 3);
    MIDSYNC; MM(1, 0, bl);
    if (full) { VMW(4); }
    ENDB;
  }
#undef ST_A
#undef ST_B
#undef RD_A
#undef RD_B
#undef MM
#undef MIDSYNC
#undef ENDB

  // ---- epilogue: acc[mf] row = wm*128 + (mf>>2)*64 + (mf&3)*16 ----
#pragma unroll
  for (int mf = 0; mf < 8; ++mf) {
#pragma unroll
    for (int nf = 0; nf < 4; ++nf) {
      int col = n0 + wn * 64 + nf * 16 + frow;
#pragma unroll
      for (int j = 0; j < 4; ++j) {
        int rl = wm * 128 + (mf >> 2) * 64 + (mf & 3) * 16 + klane * 4 + j;
        int grow = m0 + rl;
        if (grow < cnt) {
          if (MODE == 0) {
            ((unsigned short*)Out)[(size_t)(base_e + grow) * N + col] = f2bf(acc[mf][nf][j]);
          } else {
            float wv = roww[base_e + grow];
            ((float*)Out)[(size_t)(base_e + grow) * N + col] = acc[mf][nf][j] * wv;
          }
        }
      }
    }
  }
}

// H = silu(h1) * h3, elementwise, in-place capable (out == h1)
__global__ __launch_bounds__(256) void swiglu_kernel(const unsigned short* __restrict__ h1,
                                                     const unsigned short* __restrict__ h3,
                                                     unsigned short* __restrict__ H, int n8) {
  int i = blockIdx.x * 256 + threadIdx.x;
  if (i >= n8) return;
  u16x8 v1 = *(const u16x8*)(h1 + (size_t)i * 8);
  u16x8 v3 = *(const u16x8*)(h3 + (size_t)i * 8);
  u16x8 o;
#pragma unroll
  for (int j = 0; j < 8; ++j) {
    float s = bf2f(v1[j]);
    float g = bf2f(v3[j]);
    o[j] = f2bf((s / (1.f + __expf(-s))) * g);
  }
  *(u16x8*)(H + (size_t)i * 8) = o;
}

// y[t,:] = R[row0(t),:] + R[row1(t),:]
__global__ __launch_bounds__(256) void combine_kernel(const float* __restrict__ R,
                                                      const int* __restrict__ rowof,
                                                      float* __restrict__ y) {
  int idx = blockIdx.x * 256 + threadIdx.x;
  int t = idx >> 9;                           // D/4 = 512
  int d4 = idx & 511;
  int r0 = rowof[t * 2], r1 = rowof[t * 2 + 1];
  f32x4 a = *(const f32x4*)(R + (size_t)r0 * DIM + d4 * 4);
  f32x4 b = *(const f32x4*)(R + (size_t)r1 * DIM + d4 * 4);
  *(f32x4*)(y + (size_t)t * DIM + d4 * 4) = a + b;
}

extern "C" void kernel_launch(void* const* d_in, const int* in_sizes, int n_in,
                              void* d_out, int out_size, void* d_ws, size_t ws_size,
                              hipStream_t stream) {
  const float* x      = (const float*)d_in[0];
  const float* gate_w = (const float*)d_in[1];
  const float* w1     = (const float*)d_in[2];
  const float* w2     = (const float*)d_in[3];
  const float* w3     = (const float*)d_in[4];
  float* y = (float*)d_out;

  char* ws = (char*)d_ws;
  const size_t MB = 1ull << 20;
  // control block
  int*   tope   = (int*)(ws);
  float* topw   = (float*)(ws + (32 << 10));
  int*   rowtok = (int*)(ws + (64 << 10));
  float* roww   = (float*)(ws + (96 << 10));
  int*   rowof  = (int*)(ws + (128 << 10));
  int*   counts = (int*)(ws + (160 << 10));
  int*   basep  = counts + 32;
  int*   fillp  = counts + 64;

  unsigned short* xb  = (unsigned short*)(ws + 1 * MB);    // 16 MB
  unsigned short* H1  = (unsigned short*)(ws + 17 * MB);   // 64 MB (h1, then H in-place)
  unsigned short* H3  = (unsigned short*)(ws + 81 * MB);   // 64 MB
  unsigned short* w1b = (unsigned short*)(ws + 145 * MB);  // 128 MB
  unsigned short* w3b = (unsigned short*)(ws + 273 * MB);  // 128 MB
  unsigned short* w2b = (unsigned short*)(ws + 401 * MB);  // 128 MB (end 529)
  float*          R   = (float*)(ws + 145 * MB);           // 64 MB, aliases dead w1b

  hipMemsetAsync(counts, 0, 512, stream);
  router_kernel<<<TTOK, 256, 0, stream>>>(x, gate_w, tope, topw, counts);
  prefix_kernel<<<1, 64, 0, stream>>>(counts, basep);
  fill_kernel<<<TTOK / 256, 256, 0, stream>>>(tope, topw, basep, fillp, rowtok, roww, rowof);

  const int nw8 = NE * FF * DIM / 8;
  const int nx8 = TTOK * DIM / 8;
  cvt_kernel<<<nw8 / 256, 256, 0, stream>>>(w1, w1b, nw8);
  cvt_kernel<<<nw8 / 256, 256, 0, stream>>>(w3, w3b, nw8);
  cvt_kernel<<<nw8 / 256, 256, 0, stream>>>(w2, w2b, nw8);
  cvt_kernel<<<nx8 / 256, 256, 0, stream>>>(x, xb, nx8);

  // h1 = Xe @ w1^T ; h3 = Xe @ w3^T   (M=routed rows, N=FF, K=DIM)
  gemm8<0, DIM, FF><<<dim3(FF / BM, 16, NE), 512, 0, stream>>>(
      xb, w1b, rowtok, roww, counts, basep, (void*)H1);
  gemm8<0, DIM, FF><<<dim3(FF / BM, 16, NE), 512, 0, stream>>>(
      xb, w3b, rowtok, roww, counts, basep, (void*)H3);
  swiglu_kernel<<<TROWS * FF / 8 / 256, 256, 0, stream>>>(H1, H3, H1, TROWS * FF / 8);
  // R = roww * (H @ w2^T)   (M=routed rows, N=DIM, K=FF); w1b dead -> R aliases it
  gemm8<1, FF, DIM><<<dim3(DIM / BM, 16, NE), 512, 0, stream>>>(
      H1, w2b, rowtok, roww, counts, basep, (void*)R);
  combine_kernel<<<TTOK * DIM / 4 / 256, 256, 0, stream>>>(R, rowof, y);
}

// Round 8
// 968.485 us; speedup vs baseline: 1.2946x; 1.0185x over previous
//
#include <hip/hip_runtime.h>
#include <hip/hip_bf16.h>

#define TTOK 4096   // B*S tokens
#define DIM  2048   // hidden dim
#define FF   4096   // expert ffn dim
#define NE   8      // experts
#define TROWS 8192  // TTOK * top_k routed rows

#define BM 256
#define BK 64       // K-tile
// 8 waves: 2 in M x 4 in N

typedef __attribute__((ext_vector_type(4))) float  f32x4;
typedef __attribute__((ext_vector_type(8))) short  s16x8;
typedef __attribute__((ext_vector_type(8))) unsigned short u16x8;

__device__ __forceinline__ unsigned short f2bf(float f) {
  union { __hip_bfloat16 h; unsigned short u; } cv;
  cv.h = __float2bfloat16(f);
  return cv.u;
}
__device__ __forceinline__ float bf2f(unsigned short u) {
  union { unsigned int i; float f; } cv;
  cv.i = ((unsigned int)u) << 16;
  return cv.f;
}

// async global->LDS, 16B per lane; dest = wave-uniform base, HW adds lane*16.
__device__ __forceinline__ void gl_lds16(const void* g, void* s) {
  __builtin_amdgcn_global_load_lds(
      (__attribute__((address_space(1))) void*)(g),
      (__attribute__((address_space(3))) void*)(s), 16, 0, 0);
}

#define VMW(NN) asm volatile("s_waitcnt vmcnt(" #NN ")" ::: "memory")

// mid-phase sync: pin reads/stages before barrier, MFMA after lgkmcnt(0)
#define MIDSYNC do { \
    __builtin_amdgcn_sched_barrier(0); \
    __builtin_amdgcn_s_barrier(); \
    asm volatile("s_waitcnt lgkmcnt(0)" ::: "memory"); \
    __builtin_amdgcn_sched_barrier(0); \
  } while (0)
#define ENDB do { \
    __builtin_amdgcn_sched_barrier(0); \
    __builtin_amdgcn_s_barrier(); \
  } while (0)

// ---------------- f32 -> bf16 bulk convert (8 elems/thread) -----------------
__global__ __launch_bounds__(256) void cvt_kernel(const float* __restrict__ s,
                                                  unsigned short* __restrict__ d, int n8) {
  int i = blockIdx.x * 256 + threadIdx.x;
  if (i >= n8) return;
  f32x4 v0 = *(const f32x4*)(s + (size_t)i * 8);
  f32x4 v1 = *(const f32x4*)(s + (size_t)i * 8 + 4);
  u16x8 o;
#pragma unroll
  for (int j = 0; j < 4; ++j) { o[j] = f2bf(v0[j]); o[j + 4] = f2bf(v1[j]); }
  *(u16x8*)(d + (size_t)i * 8) = o;
}

// ---------------- router ----------------------------------------------------
__global__ void router_kernel(const float* __restrict__ x,
                              const float* __restrict__ gate_w,
                              int* __restrict__ tope, float* __restrict__ topw,
                              int* __restrict__ counts) {
  const int t = blockIdx.x;
  const int tid = threadIdx.x;
  const float* xr = x + (size_t)t * DIM;
  float p[NE];
#pragma unroll
  for (int e = 0; e < NE; ++e) p[e] = 0.f;
  for (int d = tid; d < DIM; d += 256) {
    float xv = xr[d];
#pragma unroll
    for (int e = 0; e < NE; ++e) p[e] += xv * gate_w[e * DIM + d];
  }
#pragma unroll
  for (int off = 32; off > 0; off >>= 1) {
#pragma unroll
    for (int e = 0; e < NE; ++e) p[e] += __shfl_down(p[e], off);
  }
  __shared__ float red[4][NE];
  const int wid = tid >> 6, lane = tid & 63;
  if (lane == 0) {
#pragma unroll
    for (int e = 0; e < NE; ++e) red[wid][e] = p[e];
  }
  __syncthreads();
  if (tid == 0) {
    float l[NE];
#pragma unroll
    for (int e = 0; e < NE; ++e) l[e] = red[0][e] + red[1][e] + red[2][e] + red[3][e];
    float mx = l[0];
#pragma unroll
    for (int e = 1; e < NE; ++e) mx = fmaxf(mx, l[e]);
    float pr[NE]; float sum = 0.f;
#pragma unroll
    for (int e = 0; e < NE; ++e) { pr[e] = __expf(l[e] - mx); sum += pr[e]; }
    float inv = 1.f / sum;
#pragma unroll
    for (int e = 0; e < NE; ++e) pr[e] *= inv;
    int i0 = 0; float p0 = pr[0];
#pragma unroll
    for (int e = 1; e < NE; ++e) if (pr[e] > p0) { p0 = pr[e]; i0 = e; }
    int i1 = -1; float p1 = -1.f;
#pragma unroll
    for (int e = 0; e < NE; ++e) if (e != i0 && pr[e] > p1) { p1 = pr[e]; i1 = e; }
    float wsum = p0 + p1;
    tope[t * 2 + 0] = i0; topw[t * 2 + 0] = p0 / wsum;
    tope[t * 2 + 1] = i1; topw[t * 2 + 1] = p1 / wsum;
    atomicAdd(&counts[i0], 1);
    atomicAdd(&counts[i1], 1);
  }
}

__global__ void prefix_kernel(const int* __restrict__ counts, int* __restrict__ basep) {
  if (threadIdx.x == 0 && blockIdx.x == 0) {
    int acc = 0;
    for (int e = 0; e < NE; ++e) { basep[e] = acc; acc += counts[e]; }
  }
}

__global__ void fill_kernel(const int* __restrict__ tope, const float* __restrict__ topw,
                            const int* __restrict__ basep, int* __restrict__ fillp,
                            int* __restrict__ rowtok, float* __restrict__ roww,
                            int* __restrict__ rowof) {
  int t = blockIdx.x * blockDim.x + threadIdx.x;
  if (t >= TTOK) return;
#pragma unroll
  for (int s = 0; s < 2; ++s) {
    int e = tope[t * 2 + s];
    int r = basep[e] + atomicAdd(&fillp[e], 1);
    rowtok[r] = t;
    roww[r] = topw[t * 2 + s];
    rowof[t * 2 + s] = r;
  }
}

// ====== fused GEMM1: H = silu(Xe@w1^T) * (Xe@w3^T), 256x128, 8-phase ========
// ROUND-6-PROVEN LEDGER: A(t+1) -> OPPOSITE buffer at p1/p2 (gated by VMW(4)
// at p4, 3-phase distance before first p5 read); B1(t+2)/B3(t+2) -> same
// buffer at p3/p4, strictly after their phase-reads (p1/p2; frags reg-held).
// Outstanding: 8 at p4 -> VMW(4) drains A(t+1); 12 at p8 -> VMW(4) drains
// B1,B3,A of t+2. Never vmcnt(0) in steady loop.
__global__ __launch_bounds__(512, 1) void gemm1f(
    const unsigned short* __restrict__ xb, const unsigned short* __restrict__ w1b,
    const unsigned short* __restrict__ w3b, const int* __restrict__ rowtok,
    const int* __restrict__ counts, const int* __restrict__ basep,
    unsigned short* __restrict__ H) {
  // ---- T1 bijective XCD chunk remap (x-fastest within chunk) ----
  constexpr int GX = FF / 128;     // 32
  constexpr int GY = TTOK / BM;    // 16
  constexpr int Q  = GX * GY;      // nwg/8
  int lin = (blockIdx.z * GY + blockIdx.y) * GX + blockIdx.x;
  int wg = (lin & 7) * Q + (lin >> 3);
  const int e   = wg / (GX * GY);
  const int rem = wg % (GX * GY);
  const int m0  = (rem / GX) * BM;
  const int n0  = (rem % GX) * 128;

  const int cnt = counts[e];
  if (m0 >= cnt) return;
  const int base_e = basep[e];

  __shared__ unsigned short As[2][BM * BK];    // 2 x 32 KiB
  __shared__ unsigned short B1s[2][128 * BK];  // 2 x 16 KiB
  __shared__ unsigned short B3s[2][128 * BK];  // 2 x 16 KiB

  const int tid = threadIdx.x;
  const int lane = tid & 63;
  const int w = tid >> 6;          // 0..7
  const int wm = w >> 2;           // 0..1  (M half)
  const int wn = w & 3;            // 0..3  (N quarter of 128)

  const int lsub  = lane >> 3;     // row within 8-row group
  const int lslot = lane & 7;      // 16B slot within 128B row
  const int swz_e = 8 * (lslot ^ lsub);   // pre-swizzled source slot

  const unsigned short* pA[4];
  const unsigned short* pB1[2];
  const unsigned short* pB3[2];
#pragma unroll
  for (int s = 0; s < 4; ++s) {
    int rl = s * 64 + w * 8 + lsub;
    int ga = m0 + rl; if (ga > cnt - 1) ga = cnt - 1;
    int tok = rowtok[base_e + ga];
    pA[s] = xb + (size_t)tok * DIM + swz_e;
  }
#pragma unroll
  for (int s = 0; s < 2; ++s) {
    int rl = s * 64 + w * 8 + lsub;
    pB1[s] = w1b + ((size_t)e * FF + n0 + rl) * DIM + swz_e;
    pB3[s] = w3b + ((size_t)e * FF + n0 + rl) * DIM + swz_e;
  }

  const int frow = lane & 15;
  const int klane = lane >> 4;     // 0..3
  const int ks0 = (klane * 8) ^ ((frow & 7) * 8);
  const int ks1 = (32 + klane * 8) ^ ((frow & 7) * 8);

  f32x4 acc1[8][2], acc3[8][2];
#pragma unroll
  for (int mf = 0; mf < 8; ++mf)
#pragma unroll
    for (int nf = 0; nf < 2; ++nf) { acc1[mf][nf] = (f32x4)0.f; acc3[mf][nf] = (f32x4)0.f; }

#define ST_A(BUF, G0, T) do { \
    gl_lds16(pA[G0]     + (size_t)(T) * BK, &As[BUF][((G0) * 64 + w * 8) * BK]); \
    gl_lds16(pA[(G0)+1] + (size_t)(T) * BK, &As[BUF][(((G0)+1) * 64 + w * 8) * BK]); \
  } while (0)
#define ST_B1(BUF, T) do { \
    gl_lds16(pB1[0] + (size_t)(T) * BK, &B1s[BUF][(0  + w * 8) * BK]); \
    gl_lds16(pB1[1] + (size_t)(T) * BK, &B1s[BUF][(64 + w * 8) * BK]); \
  } while (0)
#define ST_B3(BUF, T) do { \
    gl_lds16(pB3[0] + (size_t)(T) * BK, &B3s[BUF][(0  + w * 8) * BK]); \
    gl_lds16(pB3[1] + (size_t)(T) * BK, &B3s[BUF][(64 + w * 8) * BK]); \
  } while (0)

#define RD_A(MH, BUF) do { \
    _Pragma("unroll") \
    for (int ii = 0; ii < 4; ++ii) { \
      a[ii][0] = *(const s16x8*)&As[BUF][(wm * 128 + (MH) * 64 + ii * 16 + frow) * BK + ks0]; \
      a[ii][1] = *(const s16x8*)&As[BUF][(wm * 128 + (MH) * 64 + ii * 16 + frow) * BK + ks1]; \
    } } while (0)
#define RD_BX(DST, ARR, BUF) do { \
    _Pragma("unroll") \
    for (int j = 0; j < 2; ++j) { \
      DST[j][0] = *(const s16x8*)&ARR[BUF][(wn * 32 + j * 16 + frow) * BK + ks0]; \
      DST[j][1] = *(const s16x8*)&ARR[BUF][(wn * 32 + j * 16 + frow) * BK + ks1]; \
    } } while (0)

#define MMX(ACC, MH, BB) do { \
    __builtin_amdgcn_s_setprio(1); \
    _Pragma("unroll") \
    for (int ii = 0; ii < 4; ++ii) \
      _Pragma("unroll") \
      for (int j = 0; j < 2; ++j) { \
        ACC[(MH) * 4 + ii][j] = __builtin_amdgcn_mfma_f32_16x16x32_bf16( \
            a[ii][0], BB[j][0], ACC[(MH) * 4 + ii][j], 0, 0, 0); \
        ACC[(MH) * 4 + ii][j] = __builtin_amdgcn_mfma_f32_16x16x32_bf16( \
            a[ii][1], BB[j][1], ACC[(MH) * 4 + ii][j], 0, 0, 0); \
      } \
    __builtin_amdgcn_s_setprio(0); \
  } while (0)

  const int NT = DIM / BK;   // 32

  // ---- prologue: A(0),B1(0),B3(0) -> buf0; B1(1),B3(1) -> buf1 ----
  // age order: A0(4), B1_0(2), B3_0(2), B1_1(2), B3_1(2) = 12; VMW(4) -> tile0 resident
  ST_A(0, 0, 0); ST_A(0, 2, 0);
  ST_B1(0, 0); ST_B3(0, 0);
  ST_B1(1, 1); ST_B3(1, 1);
  VMW(4);
  __builtin_amdgcn_s_barrier();

  s16x8 a[4][2], bl[2][2], bh[2][2];

  for (int t = 0; t < NT; t += 2) {
    const bool full = (t + 2 < NT);

    // ===== tile t (buf0) =====
    // p1: (mlo,B1); stage A-lo(t+1) -> buf1
    RD_A(0, 0); RD_BX(bl, B1s, 0);
    ST_A(1, 0, t + 1);
    MIDSYNC; MMX(acc1, 0, bl); ENDB;
    // p2: (mlo,B3); stage A-hi(t+1) -> buf1
    RD_BX(bh, B3s, 0);
    ST_A(1, 2, t + 1);
    MIDSYNC; MMX(acc3, 0, bh); ENDB;
    // p3: (mhi,B3); stage B1(t+2) -> buf0 (B1s[0] last read at p1)
    RD_A(1, 0);
    if (full) ST_B1(0, t + 2);
    MIDSYNC; MMX(acc3, 1, bh); ENDB;
    // p4: (mhi,B1); stage B3(t+2) -> buf0; gate: drain A(t+1)
    if (full) ST_B3(0, t + 2);
    MIDSYNC; MMX(acc1, 1, bl);
    if (full) { VMW(4); } else { VMW(0); }
    ENDB;

    // ===== tile t+1 (buf1) =====
    // p5: stage A-lo(t+2) -> buf0
    RD_A(0, 1); RD_BX(bl, B1s, 1);
    if (full) ST_A(0, 0, t + 2);
    MIDSYNC; MMX(acc1, 0, bl); ENDB;
    // p6: stage A-hi(t+2) -> buf0
    RD_BX(bh, B3s, 1);
    if (full) ST_A(0, 2, t + 2);
    MIDSYNC; MMX(acc3, 0, bh); ENDB;
    // p7: stage B1(t+3) -> buf1
    RD_A(1, 1);
    if (full) ST_B1(1, t + 3);
    MIDSYNC; MMX(acc3, 1, bh); ENDB;
    // p8: stage B3(t+3) -> buf1; gate: drain B1,B3,A of t+2
    if (full) ST_B3(1, t + 3);
    MIDSYNC; MMX(acc1, 1, bl);
    if (full) { VMW(4); }
    ENDB;
  }
#undef ST_A
#undef ST_B1
#undef ST_B3
#undef RD_A
#undef RD_BX
#undef MMX

  // ---- epilogue: SwiGLU fused; row = wm*128 + (mf>>2)*64 + (mf&3)*16 ----
#pragma unroll
  for (int mf = 0; mf < 8; ++mf) {
#pragma unroll
    for (int nf = 0; nf < 2; ++nf) {
      int col = n0 + wn * 32 + nf * 16 + frow;
      f32x4 c1 = acc1[mf][nf], c3 = acc3[mf][nf];
#pragma unroll
      for (int j = 0; j < 4; ++j) {
        int rl = wm * 128 + (mf >> 2) * 64 + (mf & 3) * 16 + klane * 4 + j;
        int grow = m0 + rl;
        if (grow < cnt) {
          float s = c1[j];
          float hval = (s / (1.f + __expf(-s))) * c3[j];
          H[(size_t)(base_e + grow) * FF + col] = f2bf(hval);
        }
      }
    }
  }
}

// ====== GEMM2: R = roww * (H @ w2^T), 256x256, round-6 8-phase + T1 =========
template <int K, int N>
__global__ __launch_bounds__(512, 1) void gemm8(
    const unsigned short* __restrict__ Asrc, const unsigned short* __restrict__ Bw,
    const float* __restrict__ roww, const int* __restrict__ counts,
    const int* __restrict__ basep, float* __restrict__ Out) {
  // ---- T1 bijective XCD chunk remap ----
  constexpr int GX = N / BM;       // 8
  constexpr int GY = TTOK / BM;    // 16
  constexpr int Q  = GX * GY;
  int lin = (blockIdx.z * GY + blockIdx.y) * GX + blockIdx.x;
  int wg = (lin & 7) * Q + (lin >> 3);
  const int e   = wg / (GX * GY);
  const int rem = wg % (GX * GY);
  const int m0  = (rem / GX) * BM;
  const int n0  = (rem % GX) * BM;

  const int cnt = counts[e];
  if (m0 >= cnt) return;
  const int base_e = basep[e];

  __shared__ unsigned short As[2][BM * BK];
  __shared__ unsigned short Bs[2][BM * BK];

  const int tid = threadIdx.x;
  const int lane = tid & 63;
  const int w = tid >> 6;
  const int wm = w >> 2;
  const int wn = w & 3;

  const int lsub  = lane >> 3;
  const int lslot = lane & 7;
  const int swz_e = 8 * (lslot ^ lsub);

  const unsigned short* pA[4];
  const unsigned short* pB[4];
#pragma unroll
  for (int s = 0; s < 4; ++s) {
    int rl = s * 64 + w * 8 + lsub;
    int ga = m0 + rl; if (ga > cnt - 1) ga = cnt - 1;
    pA[s] = Asrc + (size_t)(base_e + ga) * K + swz_e;
    pB[s] = Bw + ((size_t)e * N + n0 + rl) * K + swz_e;
  }

  const int frow = lane & 15;
  const int klane = lane >> 4;
  const int ks0 = (klane * 8) ^ ((frow & 7) * 8);
  const int ks1 = (32 + klane * 8) ^ ((frow & 7) * 8);

  f32x4 acc[8][4];
#pragma unroll
  for (int mf = 0; mf < 8; ++mf)
#pragma unroll
    for (int nf = 0; nf < 4; ++nf) acc[mf][nf] = (f32x4)0.f;

#define ST_A(BUF, G0, T) do { \
    gl_lds16(pA[G0]     + (size_t)(T) * BK, &As[BUF][((G0) * 64 + w * 8) * BK]); \
    gl_lds16(pA[(G0)+1] + (size_t)(T) * BK, &As[BUF][(((G0)+1) * 64 + w * 8) * BK]); \
  } while (0)
#define ST_B(BUF, G0, T) do { \
    gl_lds16(pB[G0]     + (size_t)(T) * BK, &Bs[BUF][((G0) * 64 + w * 8) * BK]); \
    gl_lds16(pB[(G0)+1] + (size_t)(T) * BK, &Bs[BUF][(((G0)+1) * 64 + w * 8) * BK]); \
  } while (0)

#define RD_A(MH, BUF) do { \
    _Pragma("unroll") \
    for (int ii = 0; ii < 4; ++ii) { \
      a[ii][0] = *(const s16x8*)&As[BUF][(wm * 128 + (MH) * 64 + ii * 16 + frow) * BK + ks0]; \
      a[ii][1] = *(const s16x8*)&As[BUF][(wm * 128 + (MH) * 64 + ii * 16 + frow) * BK + ks1]; \
    } } while (0)
#define RD_B(DST, NH, BUF) do { \
    _Pragma("unroll") \
    for (int j = 0; j < 2; ++j) { \
      DST[j][0] = *(const s16x8*)&Bs[BUF][(wn * 64 + (NH) * 32 + j * 16 + frow) * BK + ks0]; \
      DST[j][1] = *(const s16x8*)&Bs[BUF][(wn * 64 + (NH) * 32 + j * 16 + frow) * BK + ks1]; \
    } } while (0)

#define MM(MH, NH, BB) do { \
    __builtin_amdgcn_s_setprio(1); \
    _Pragma("unroll") \
    for (int ii = 0; ii < 4; ++ii) \
      _Pragma("unroll") \
      for (int j = 0; j < 2; ++j) { \
        acc[(MH) * 4 + ii][(NH) * 2 + j] = __builtin_amdgcn_mfma_f32_16x16x32_bf16( \
            a[ii][0], BB[j][0], acc[(MH) * 4 + ii][(NH) * 2 + j], 0, 0, 0); \
        acc[(MH) * 4 + ii][(NH) * 2 + j] = __builtin_amdgcn_mfma_f32_16x16x32_bf16( \
            a[ii][1], BB[j][1], acc[(MH) * 4 + ii][(NH) * 2 + j], 0, 0, 0); \
      } \
    __builtin_amdgcn_s_setprio(0); \
  } while (0)

  const int NT = K / BK;

  ST_A(0, 0, 0); ST_A(0, 2, 0);
  ST_B(0, 0, 0); ST_B(0, 2, 0);
  ST_B(1, 0, 1); ST_B(1, 2, 1);
  VMW(4);
  __builtin_amdgcn_s_barrier();

  s16x8 a[4][2], bl[2][2], bh[2][2];

  for (int t = 0; t < NT; t += 2) {
    const bool full = (t + 2 < NT);

    RD_A(0, 0); RD_B(bl, 0, 0);
    ST_A(1, 0, t + 1);
    MIDSYNC; MM(0, 0, bl); ENDB;

    RD_B(bh, 1, 0);
    ST_A(1, 2, t + 1);
    MIDSYNC; MM(0, 1, bh); ENDB;

    RD_A(1, 0);
    if (full) ST_B(0, 0, t + 2);
    MIDSYNC; MM(1, 1, bh); ENDB;

    if (full) ST_B(0, 2, t + 2);
    MIDSYNC; MM(1, 0, bl);
    if (full) { VMW(4); } else { VMW(0); }
    ENDB;

    RD_A(0, 1); RD_B(bl, 0, 1);
    if (full) ST_A(0, 0, t + 2);
    MIDSYNC; MM(0, 0, bl); ENDB;

    RD_B(bh, 1, 1);
    if (full) ST_A(0, 2, t + 2);
    MIDSYNC; MM(0, 1, bh); ENDB;

    RD_A(1, 1);
    if (full) ST_B(1, 0, t + 3);
    MIDSYNC; MM(1, 1, bh); ENDB;

    if (full) ST_B(1, 2, t + 3);
    MIDSYNC; MM(1, 0, bl);
    if (full) { VMW(4); }
    ENDB;
  }
#undef ST_A
#undef ST_B
#undef RD_A
#undef RD_B
#undef MM

#pragma unroll
  for (int mf = 0; mf < 8; ++mf) {
#pragma unroll
    for (int nf = 0; nf < 4; ++nf) {
      int col = n0 + wn * 64 + nf * 16 + frow;
#pragma unroll
      for (int j = 0; j < 4; ++j) {
        int rl = wm * 128 + (mf >> 2) * 64 + (mf & 3) * 16 + klane * 4 + j;
        int grow = m0 + rl;
        if (grow < cnt) {
          float wv = roww[base_e + grow];
          Out[(size_t)(base_e + grow) * N + col] = acc[mf][nf][j] * wv;
        }
      }
    }
  }
}

// y[t,:] = R[row0(t),:] + R[row1(t),:]
__global__ __launch_bounds__(256) void combine_kernel(const float* __restrict__ R,
                                                      const int* __restrict__ rowof,
                                                      float* __restrict__ y) {
  int idx = blockIdx.x * 256 + threadIdx.x;
  int t = idx >> 9;                           // D/4 = 512
  int d4 = idx & 511;
  int r0 = rowof[t * 2], r1 = rowof[t * 2 + 1];
  f32x4 a = *(const f32x4*)(R + (size_t)r0 * DIM + d4 * 4);
  f32x4 b = *(const f32x4*)(R + (size_t)r1 * DIM + d4 * 4);
  *(f32x4*)(y + (size_t)t * DIM + d4 * 4) = a + b;
}

extern "C" void kernel_launch(void* const* d_in, const int* in_sizes, int n_in,
                              void* d_out, int out_size, void* d_ws, size_t ws_size,
                              hipStream_t stream) {
  const float* x      = (const float*)d_in[0];
  const float* gate_w = (const float*)d_in[1];
  const float* w1     = (const float*)d_in[2];
  const float* w2     = (const float*)d_in[3];
  const float* w3     = (const float*)d_in[4];
  float* y = (float*)d_out;

  char* ws = (char*)d_ws;
  const size_t MB = 1ull << 20;
  int*   tope   = (int*)(ws);
  float* topw   = (float*)(ws + (32 << 10));
  int*   rowtok = (int*)(ws + (64 << 10));
  float* roww   = (float*)(ws + (96 << 10));
  int*   rowof  = (int*)(ws + (128 << 10));
  int*   counts = (int*)(ws + (160 << 10));
  int*   basep  = counts + 32;
  int*   fillp  = counts + 64;

  unsigned short* xb  = (unsigned short*)(ws + 1 * MB);    // 16 MB
  unsigned short* H1  = (unsigned short*)(ws + 17 * MB);   // 64 MB (fused H)
  unsigned short* w1b = (unsigned short*)(ws + 145 * MB);  // 128 MB
  unsigned short* w3b = (unsigned short*)(ws + 273 * MB);  // 128 MB
  unsigned short* w2b = (unsigned short*)(ws + 401 * MB);  // 128 MB (end 529)
  float*          R   = (float*)(ws + 81 * MB);            // 64 MB

  hipMemsetAsync(counts, 0, 512, stream);
  router_kernel<<<TTOK, 256, 0, stream>>>(x, gate_w, tope, topw, counts);
  prefix_kernel<<<1, 64, 0, stream>>>(counts, basep);
  fill_kernel<<<TTOK / 256, 256, 0, stream>>>(tope, topw, basep, fillp, rowtok, roww, rowof);

  const int nw8 = NE * FF * DIM / 8;
  const int nx8 = TTOK * DIM / 8;
  cvt_kernel<<<nw8 / 256, 256, 0, stream>>>(w1, w1b, nw8);
  cvt_kernel<<<nw8 / 256, 256, 0, stream>>>(w3, w3b, nw8);
  cvt_kernel<<<nw8 / 256, 256, 0, stream>>>(w2, w2b, nw8);
  cvt_kernel<<<nx8 / 256, 256, 0, stream>>>(x, xb, nx8);

  // fused: H = silu(Xe@w1^T) * (Xe@w3^T)
  gemm1f<<<dim3(FF / 128, TTOK / BM, NE), 512, 0, stream>>>(
      xb, w1b, w3b, rowtok, counts, basep, H1);
  // R = roww * (H @ w2^T)
  gemm8<FF, DIM><<<dim3(DIM / BM, TTOK / BM, NE), 512, 0, stream>>>(
      H1, w2b, roww, counts, basep, R);
  combine_kernel<<<TTOK * DIM / 4 / 256, 256, 0, stream>>>(R, rowof, y);
}